// Round 1
// baseline (650.871 us; speedup 1.0000x reference)
//
#include <hip/hip_runtime.h>

typedef unsigned short ushort_t;
typedef __attribute__((ext_vector_type(8))) __bf16 bf16x8;
typedef __attribute__((ext_vector_type(4))) float f32x4;

#define HD 128
#define NL 4

__device__ __forceinline__ ushort_t f2bf(float f){
  unsigned u = __builtin_bit_cast(unsigned, f);
  unsigned r = (u + 0x7FFFu + ((u >> 16) & 1u)) >> 16;
  return (ushort_t)r;
}

__device__ __forceinline__ f32x4 mfma16(bf16x8 a, bf16x8 b, f32x4 c){
  return __builtin_amdgcn_mfma_f32_16x16x32_bf16(a, b, c, 0, 0, 0);
}

// ---------------- prep kernels ----------------
__global__ void hist_kernel(const int* __restrict__ dst, int* __restrict__ deg, int E){
  int e = blockIdx.x * 256 + threadIdx.x;
  if (e < E) atomicAdd(&deg[dst[e]], 1);
}

__global__ void ghist_kernel(const int* __restrict__ batch, int* __restrict__ gdeg, int N){
  int n = blockIdx.x * 256 + threadIdx.x;
  if (n < N) atomicAdd(&gdeg[batch[n]], 1);
}

// single-block exclusive scan; out has n+1 entries; optionally duplicates into cur
__global__ void scan_excl(const int* __restrict__ in, int* __restrict__ out,
                          int* __restrict__ cur, int n){
  __shared__ int buf[1024];
  int tid = threadIdx.x;
  int carry = 0;
  for (int base = 0; base < n; base += 1024){
    int i = base + tid;
    int v = (i < n) ? in[i] : 0;
    __syncthreads();
    buf[tid] = v;
    __syncthreads();
    int acc = v;
    for (int o = 1; o < 1024; o <<= 1){
      int tv = (tid >= o) ? buf[tid - o] : 0;
      __syncthreads();
      acc += tv;
      buf[tid] = acc;
      __syncthreads();
    }
    int total = buf[1023];
    int excl = acc - v + carry;
    if (i < n){ out[i] = excl; if (cur) cur[i] = excl; }
    carry += total;
  }
  if (tid == 0) out[n] = carry;
}

__global__ void scatter_kernel(const int* __restrict__ src, const int* __restrict__ dst,
                               const float4* __restrict__ ea, int* __restrict__ cursor,
                               int* __restrict__ srcs_s, float4* __restrict__ ea4_s, int E){
  int e = blockIdx.x * 256 + threadIdx.x;
  if (e < E){
    int d = dst[e];
    int p = atomicAdd(&cursor[d], 1);
    srcs_s[p] = src[e];
    ea4_s[p] = ea[e];
  }
}

// W1 [L][128][256] -> W1t bf16 [L][256][128]; W2 [L][256][128] -> W2t bf16 [L][128][256]
__global__ void wconv_kernel(const float* __restrict__ W1, const float* __restrict__ W2,
                             ushort_t* __restrict__ W1t, ushort_t* __restrict__ W2t){
  int i = blockIdx.x * 256 + threadIdx.x;
  if (i < NL * 32768){
    int l = i >> 15, r = i & 32767;
    int n = r >> 7, k = r & 127;                 // W1t[l][n][k], n<256, k<128
    W1t[i] = f2bf(W1[l * 32768 + k * 256 + n]);
  } else {
    int i2 = i - NL * 32768;
    int l = i2 >> 15, r = i2 & 32767;
    int n = r >> 8, k = r & 255;                 // W2t[l][n][k], n<128, k<256
    W2t[i2] = f2bf(W2[l * 32768 + k * 128 + n]);
  }
}

// ---------------- encoder ----------------
__global__ void encoder_kernel(const float* __restrict__ x, const float* __restrict__ Wn,
                               const float* __restrict__ bn, float* __restrict__ h, int N){
  int n = blockIdx.x, j = threadIdx.x;
  float acc = bn[j];
  #pragma unroll
  for (int k = 0; k < 9; ++k) acc = fmaf(x[n * 9 + k], Wn[k * HD + j], acc);
  h[(size_t)n * HD + j] = acc;
}

// ---------------- message + aggregate:  z = bf16(h + sum_in relu(h[src] + ea)) ----------------
__global__ void agg_kernel(const float* __restrict__ h, const int* __restrict__ off,
                           const int* __restrict__ srcs, const float4* __restrict__ ea4,
                           const float* __restrict__ We, const float* __restrict__ be,
                           ushort_t* __restrict__ z, int N){
  int n = blockIdx.x, j = threadIdx.x;
  float w0 = We[j], w1 = We[HD + j], w2 = We[2 * HD + j], w3 = We[3 * HD + j];
  float bj = be[j];
  int s = off[n], e = off[n + 1];
  float acc = h[(size_t)n * HD + j];
  int sc = 0; float4 a = {0, 0, 0, 0};
  if (s < e){ sc = srcs[s]; a = ea4[s]; }
  for (int i = s; i < e; ){
    int scc = sc; float4 ac = a;
    ++i;
    if (i < e){ sc = srcs[i]; a = ea4[i]; }       // prefetch next (hide latency)
    float eav = fmaf(ac.x, w0, fmaf(ac.y, w1, fmaf(ac.z, w2, fmaf(ac.w, w3, bj))));
    float m = h[(size_t)scc * HD + j] + eav;
    acc += fmaxf(m, 0.f);
  }
  z[(size_t)n * HD + j] = f2bf(acc);
}

// ---------------- MLP GEMM 1: t = relu(z @ W1 + b1), bf16 MFMA ----------------
__global__ __launch_bounds__(256, 2) void mlp1_kernel(
    const ushort_t* __restrict__ z, const ushort_t* __restrict__ Bt,
    const float* __restrict__ bias, ushort_t* __restrict__ outp, int N){
  extern __shared__ char smem[];
  char* As = smem;              // [128 rows][128 k] bf16, XOR-swizzled, 32KB
  char* Bs = smem + 32768;      // [128 cols][128 k] bf16, XOR-swizzled, 32KB
  int tid = threadIdx.x;
  int r0 = blockIdx.x * 128;
  int c0 = blockIdx.y * 128;
  #pragma unroll
  for (int i = 0; i < 8; ++i){
    int g = i * 256 + tid;
    int row = g >> 4, kg = g & 15;
    int lb = row * 256 + ((kg * 16) ^ ((row & 7) << 4));
    int ar = min(r0 + row, N - 1);
    *(bf16x8*)(As + lb) = *(const bf16x8*)(z + (size_t)ar * 128 + kg * 8);
    *(bf16x8*)(Bs + lb) = *(const bf16x8*)(Bt + (size_t)(c0 + row) * 128 + kg * 8);
  }
  __syncthreads();
  int w = tid >> 6, l = tid & 63;
  int wr = w >> 1, wc = w & 1;
  int lr = l & 15, lk = l >> 4;
  f32x4 acc[4][4] = {};
  #pragma unroll
  for (int ks = 0; ks < 4; ++ks){
    int kb = ks * 64 + lk * 16;
    bf16x8 a[4], b[4];
    #pragma unroll
    for (int fm = 0; fm < 4; ++fm){
      int row = wr * 64 + fm * 16 + lr;
      a[fm] = *(const bf16x8*)(As + row * 256 + (kb ^ ((row & 7) << 4)));
    }
    #pragma unroll
    for (int fn = 0; fn < 4; ++fn){
      int col = wc * 64 + fn * 16 + lr;
      b[fn] = *(const bf16x8*)(Bs + col * 256 + (kb ^ ((col & 7) << 4)));
    }
    #pragma unroll
    for (int fm = 0; fm < 4; ++fm)
      #pragma unroll
      for (int fn = 0; fn < 4; ++fn)
        acc[fm][fn] = mfma16(a[fm], b[fn], acc[fm][fn]);
  }
  float bv[4];
  #pragma unroll
  for (int fn = 0; fn < 4; ++fn) bv[fn] = bias[c0 + wc * 64 + fn * 16 + lr];
  #pragma unroll
  for (int fm = 0; fm < 4; ++fm){
    #pragma unroll
    for (int r = 0; r < 4; ++r){
      int row = r0 + wr * 64 + fm * 16 + lk * 4 + r;
      if (row < N){
        #pragma unroll
        for (int fn = 0; fn < 4; ++fn){
          int col = c0 + wc * 64 + fn * 16 + lr;
          outp[(size_t)row * 256 + col] = f2bf(fmaxf(acc[fm][fn][r] + bv[fn], 0.f));
        }
      }
    }
  }
}

// ------- MLP GEMM 2 + bias + LayerNorm + relu + residual (in-place h) -------
__global__ __launch_bounds__(256, 2) void mlp2_kernel(
    const ushort_t* __restrict__ tin, const ushort_t* __restrict__ Bt,
    const float* __restrict__ b2, const float* __restrict__ gamma,
    const float* __restrict__ beta, float* __restrict__ h, int N){
  extern __shared__ char smem[];
  char* As = smem;                     // staging, 32KB (reused per K-half)
  char* Bs = smem + 32768;             // staging, 32KB
  float* z2 = (float*)smem;            // [128][130] f32, overlaps staging (used after)
  float* stat = (float*)(smem + 66560);// mean[128], rstd[128]
  int tid = threadIdx.x;
  int r0 = blockIdx.x * 128;
  int w = tid >> 6, l = tid & 63;
  int wr = w >> 1, wc = w & 1;
  int lr = l & 15, lk = l >> 4;
  f32x4 acc[4][4] = {};
  for (int kh = 0; kh < 2; ++kh){
    #pragma unroll
    for (int i = 0; i < 8; ++i){
      int g = i * 256 + tid;
      int row = g >> 4, kg = g & 15;
      int lb = row * 256 + ((kg * 16) ^ ((row & 7) << 4));
      int ar = min(r0 + row, N - 1);
      *(bf16x8*)(As + lb) = *(const bf16x8*)(tin + (size_t)ar * 256 + kh * 128 + kg * 8);
      *(bf16x8*)(Bs + lb) = *(const bf16x8*)(Bt + (size_t)row * 256 + kh * 128 + kg * 8);
    }
    __syncthreads();
    #pragma unroll
    for (int ks = 0; ks < 4; ++ks){
      int kb = ks * 64 + lk * 16;
      bf16x8 a[4], b[4];
      #pragma unroll
      for (int fm = 0; fm < 4; ++fm){
        int row = wr * 64 + fm * 16 + lr;
        a[fm] = *(const bf16x8*)(As + row * 256 + (kb ^ ((row & 7) << 4)));
      }
      #pragma unroll
      for (int fn = 0; fn < 4; ++fn){
        int col = wc * 64 + fn * 16 + lr;
        b[fn] = *(const bf16x8*)(Bs + col * 256 + (kb ^ ((col & 7) << 4)));
      }
      #pragma unroll
      for (int fm = 0; fm < 4; ++fm)
        #pragma unroll
        for (int fn = 0; fn < 4; ++fn)
          acc[fm][fn] = mfma16(a[fm], b[fn], acc[fm][fn]);
    }
    __syncthreads();
  }
  // epilogue: z2 = acc + b2 (LDS, stride 130 avoids bank conflicts)
  float bv[4];
  #pragma unroll
  for (int fn = 0; fn < 4; ++fn) bv[fn] = b2[wc * 64 + fn * 16 + lr];
  #pragma unroll
  for (int fm = 0; fm < 4; ++fm)
    #pragma unroll
    for (int r = 0; r < 4; ++r){
      int row = wr * 64 + fm * 16 + lk * 4 + r;
      #pragma unroll
      for (int fn = 0; fn < 4; ++fn){
        int col = wc * 64 + fn * 16 + lr;
        z2[row * 130 + col] = acc[fm][fn][r] + bv[fn];
      }
    }
  __syncthreads();
  // pass 1: per-row mean/rstd (2 threads per row, pair-combine via shfl)
  {
    int row = tid >> 1, hf = tid & 1;
    const float* q = z2 + row * 130 + hf * 64;
    float s = 0.f, qq = 0.f;
    #pragma unroll
    for (int i = 0; i < 32; ++i){
      float2 v = *(const float2*)(q + i * 2);
      s += v.x + v.y; qq += v.x * v.x + v.y * v.y;
    }
    s += __shfl_xor(s, 1, 64);
    qq += __shfl_xor(qq, 1, 64);
    if (hf == 0){
      float mean = s * (1.f / 128.f);
      float var = qq * (1.f / 128.f) - mean * mean;
      stat[row] = mean;
      stat[128 + row] = rsqrtf(var + 1e-5f);
    }
  }
  __syncthreads();
  // pass 2: coalesced transform + relu + residual, write h in place
  #pragma unroll 4
  for (int it = 0; it < 32; ++it){
    int row = it * 4 + (tid >> 6);
    int grow = r0 + row;
    if (grow < N){
      int col = (tid & 63) * 2;
      float2 v = *(const float2*)(z2 + row * 130 + col);
      float m = stat[row], rs = stat[128 + row];
      float2 g = *(const float2*)(gamma + col);
      float2 bt = *(const float2*)(beta + col);
      float2 hr = *(const float2*)(h + (size_t)grow * HD + col);
      float2 ov;
      ov.x = fmaxf((v.x - m) * rs * g.x + bt.x, 0.f) + hr.x;
      ov.y = fmaxf((v.y - m) * rs * g.y + bt.y, 0.f) + hr.y;
      *(float2*)(h + (size_t)grow * HD + col) = ov;
    }
  }
}

// ---------------- pool (batch is sorted -> contiguous node ranges) ----------------
__global__ void pool_kernel(const float* __restrict__ h, const int* __restrict__ goff,
                            float* __restrict__ outp, int G){
  int g = blockIdx.x, j = threadIdx.x;
  int s = goff[g], e = goff[g + 1];
  float acc = 0.f;
  for (int i = s; i < e; ++i) acc += h[(size_t)i * HD + j];
  outp[(size_t)g * HD + j] = acc;
}

extern "C" void kernel_launch(void* const* d_in, const int* in_sizes, int n_in,
                              void* d_out, int out_size, void* d_ws, size_t ws_size,
                              hipStream_t stream){
  const float* x     = (const float*)d_in[0];
  const int*   ei    = (const int*)  d_in[1];
  const float* eattr = (const float*)d_in[2];
  const int*   batch = (const int*)  d_in[3];
  const float* Wn    = (const float*)d_in[4];
  const float* bn    = (const float*)d_in[5];
  const float* We    = (const float*)d_in[6];
  const float* be    = (const float*)d_in[7];
  const float* W1    = (const float*)d_in[8];
  const float* b1    = (const float*)d_in[9];
  const float* W2    = (const float*)d_in[10];
  const float* b2    = (const float*)d_in[11];
  const float* gamma = (const float*)d_in[12];
  const float* beta  = (const float*)d_in[13];
  float* outp = (float*)d_out;

  int N = in_sizes[3];
  int E = in_sizes[2] / 4;
  int G = out_size / HD;

  char* base = (char*)d_ws;
  size_t o = 0;
  auto alloc = [&](size_t bytes)->char*{
    char* r = base + o; o = (o + bytes + 255) & ~(size_t)255; return r;
  };
  float*    h    = (float*)   alloc((size_t)N * HD * 4);
  ushort_t* z    = (ushort_t*)alloc((size_t)N * HD * 2);
  ushort_t* t    = (ushort_t*)alloc((size_t)N * 2 * HD * 2);
  ushort_t* W1t  = (ushort_t*)alloc((size_t)NL * 2 * HD * HD * 2);
  ushort_t* W2t  = (ushort_t*)alloc((size_t)NL * 2 * HD * HD * 2);
  int* deg    = (int*)alloc((size_t)N * 4);
  int* gdeg   = (int*)alloc((size_t)G * 4);
  int* off    = (int*)alloc((size_t)(N + 1) * 4);
  int* goff   = (int*)alloc((size_t)(G + 1) * 4);
  int* cursor = (int*)alloc((size_t)N * 4);
  int* srcs_s = (int*)alloc((size_t)E * 4);
  float4* ea4 = (float4*)alloc((size_t)E * 16);
  (void)ws_size; (void)n_in;

  const int* src = ei;
  const int* dst = ei + E;

  hipMemsetAsync(deg, 0, (size_t)N * 4, stream);
  hipMemsetAsync(gdeg, 0, (size_t)G * 4, stream);

  hist_kernel<<<(E + 255) / 256, 256, 0, stream>>>(dst, deg, E);
  ghist_kernel<<<(N + 255) / 256, 256, 0, stream>>>(batch, gdeg, N);
  scan_excl<<<1, 1024, 0, stream>>>(deg, off, cursor, N);
  scan_excl<<<1, 1024, 0, stream>>>(gdeg, goff, (int*)nullptr, G);
  scatter_kernel<<<(E + 255) / 256, 256, 0, stream>>>(src, dst, (const float4*)eattr,
                                                      cursor, srcs_s, ea4, E);
  wconv_kernel<<<(2 * NL * 32768) / 256, 256, 0, stream>>>(W1, W2, W1t, W2t);
  encoder_kernel<<<N, HD, 0, stream>>>(x, Wn, bn, h, N);

  int mblocks = (N + 127) / 128;
  for (int l = 0; l < NL; ++l){
    agg_kernel<<<N, HD, 0, stream>>>(h, off, srcs_s, ea4, We, be, z, N);
    mlp1_kernel<<<dim3(mblocks, 2), 256, 65536, stream>>>(
        z, W1t + (size_t)l * 2 * HD * HD, b1 + l * 2 * HD, t, N);
    mlp2_kernel<<<mblocks, 256, 67584, stream>>>(
        t, W2t + (size_t)l * 2 * HD * HD, b2 + l * HD, gamma + l * HD, beta + l * HD, h, N);
  }
  pool_kernel<<<G, HD, 0, stream>>>(h, goff, outp, G);
}

// Round 2
// 537.405 us; speedup vs baseline: 1.2111x; 1.2111x over previous
//
#include <hip/hip_runtime.h>

typedef unsigned short ushort_t;
typedef __attribute__((ext_vector_type(8))) __bf16 bf16x8;
typedef __attribute__((ext_vector_type(4))) float f32x4;

#define HD 128
#define NL 4

__device__ __forceinline__ ushort_t f2bf(float f){
  unsigned u = __builtin_bit_cast(unsigned, f);
  unsigned r = (u + 0x7FFFu + ((u >> 16) & 1u)) >> 16;
  return (ushort_t)r;
}

__device__ __forceinline__ float bf2f(ushort_t u){
  unsigned v = ((unsigned)u) << 16;
  return __builtin_bit_cast(float, v);
}

__device__ __forceinline__ f32x4 mfma16(bf16x8 a, bf16x8 b, f32x4 c){
  return __builtin_amdgcn_mfma_f32_16x16x32_bf16(a, b, c, 0, 0, 0);
}

// ---------------- prep kernels ----------------
__global__ void hist_kernel(const int* __restrict__ dst, int* __restrict__ deg, int E){
  int e = blockIdx.x * 256 + threadIdx.x;
  if (e < E) atomicAdd(&deg[dst[e]], 1);
}

__global__ void ghist_kernel(const int* __restrict__ batch, int* __restrict__ gdeg, int N){
  int n = blockIdx.x * 256 + threadIdx.x;
  if (n < N) atomicAdd(&gdeg[batch[n]], 1);
}

// single-block exclusive scan, 1024 threads, thread-chunked (2 barriers total).
// out has n+1 entries; optionally duplicates into cur.
__global__ void scan_excl(const int* __restrict__ in, int* __restrict__ out,
                          int* __restrict__ cur, int n){
  __shared__ int wsum[16];
  int tid = threadIdx.x;
  int chunk = (n + 1023) >> 10;
  int beg = tid * chunk;
  int end = min(beg + chunk, n);
  int sum = 0;
  for (int i = beg; i < end; ++i) sum += in[i];
  int lane = tid & 63, wid = tid >> 6;
  int v = sum;
  #pragma unroll
  for (int o = 1; o < 64; o <<= 1){
    int t = __shfl_up(v, o, 64);
    if (lane >= o) v += t;
  }
  if (lane == 63) wsum[wid] = v;
  __syncthreads();
  if (wid == 0){
    int wv = (lane < 16) ? wsum[lane] : 0;
    #pragma unroll
    for (int o = 1; o < 16; o <<= 1){
      int t = __shfl_up(wv, o, 64);
      if (lane >= o) wv += t;
    }
    if (lane < 16) wsum[lane] = wv;
  }
  __syncthreads();
  int excl = v - sum + (wid ? wsum[wid - 1] : 0);
  int run = excl;
  for (int i = beg; i < end; ++i){
    out[i] = run;
    if (cur) cur[i] = run;
    run += in[i];
  }
  if (tid == 0) out[n] = wsum[15];
}

__global__ void scatter_kernel(const int* __restrict__ src, const int* __restrict__ dst,
                               const float4* __restrict__ ea, int* __restrict__ cursor,
                               int* __restrict__ srcs_s, float4* __restrict__ ea4_s, int E){
  int e = blockIdx.x * 256 + threadIdx.x;
  if (e < E){
    int d = dst[e];
    int p = atomicAdd(&cursor[d], 1);
    srcs_s[p] = src[e];
    ea4_s[p] = ea[e];
  }
}

// W1 [L][128][256] -> W1t bf16 [L][256][128]; W2 [L][256][128] -> W2t bf16 [L][128][256]
__global__ void wconv_kernel(const float* __restrict__ W1, const float* __restrict__ W2,
                             ushort_t* __restrict__ W1t, ushort_t* __restrict__ W2t){
  int i = blockIdx.x * 256 + threadIdx.x;
  if (i < NL * 32768){
    int l = i >> 15, r = i & 32767;
    int n = r >> 7, k = r & 127;                 // W1t[l][n][k], n<256, k<128
    W1t[i] = f2bf(W1[l * 32768 + k * 256 + n]);
  } else {
    int i2 = i - NL * 32768;
    int l = i2 >> 15, r = i2 & 32767;
    int n = r >> 8, k = r & 255;                 // W2t[l][n][k], n<128, k<256
    W2t[i2] = f2bf(W2[l * 32768 + k * 128 + n]);
  }
}

// ---------------- encoder ----------------
__global__ void encoder_kernel(const float* __restrict__ x, const float* __restrict__ Wn,
                               const float* __restrict__ bn, float* __restrict__ h,
                               ushort_t* __restrict__ hb, int N){
  int n = blockIdx.x, j = threadIdx.x;
  float acc = bn[j];
  #pragma unroll
  for (int k = 0; k < 9; ++k) acc = fmaf(x[n * 9 + k], Wn[k * HD + j], acc);
  h[(size_t)n * HD + j] = acc;
  hb[(size_t)n * HD + j] = f2bf(acc);
}

// ------- message + aggregate:  z = bf16(h + sum_in relu(hb[src] + ea)) -------
// 4-wide edge unroll: 4 independent bf16 gathers in flight per iteration.
__global__ void agg_kernel(const float* __restrict__ h, const ushort_t* __restrict__ hb,
                           const int* __restrict__ off, const int* __restrict__ srcs,
                           const float4* __restrict__ ea4, const float* __restrict__ We,
                           const float* __restrict__ be, ushort_t* __restrict__ z, int N){
  int n = blockIdx.x, j = threadIdx.x;
  float w0 = We[j], w1 = We[HD + j], w2 = We[2 * HD + j], w3 = We[3 * HD + j];
  float bj = be[j];
  int s = off[n], e = off[n + 1];
  float acc = h[(size_t)n * HD + j];
  int i = s;
  for (; i + 4 <= e; i += 4){
    int s0 = srcs[i], s1 = srcs[i + 1], s2 = srcs[i + 2], s3 = srcs[i + 3];
    float4 a0 = ea4[i], a1 = ea4[i + 1], a2 = ea4[i + 2], a3 = ea4[i + 3];
    float h0 = bf2f(hb[(size_t)s0 * HD + j]);
    float h1 = bf2f(hb[(size_t)s1 * HD + j]);
    float h2 = bf2f(hb[(size_t)s2 * HD + j]);
    float h3 = bf2f(hb[(size_t)s3 * HD + j]);
    float e0 = fmaf(a0.x, w0, fmaf(a0.y, w1, fmaf(a0.z, w2, fmaf(a0.w, w3, bj))));
    float e1 = fmaf(a1.x, w0, fmaf(a1.y, w1, fmaf(a1.z, w2, fmaf(a1.w, w3, bj))));
    float e2 = fmaf(a2.x, w0, fmaf(a2.y, w1, fmaf(a2.z, w2, fmaf(a2.w, w3, bj))));
    float e3 = fmaf(a3.x, w0, fmaf(a3.y, w1, fmaf(a3.z, w2, fmaf(a3.w, w3, bj))));
    acc += fmaxf(h0 + e0, 0.f);
    acc += fmaxf(h1 + e1, 0.f);
    acc += fmaxf(h2 + e2, 0.f);
    acc += fmaxf(h3 + e3, 0.f);
  }
  for (; i < e; ++i){
    int sc = srcs[i];
    float4 a = ea4[i];
    float eav = fmaf(a.x, w0, fmaf(a.y, w1, fmaf(a.z, w2, fmaf(a.w, w3, bj))));
    acc += fmaxf(bf2f(hb[(size_t)sc * HD + j]) + eav, 0.f);
  }
  z[(size_t)n * HD + j] = f2bf(acc);
}

// ---------------- MLP GEMM 1: t = relu(z @ W1 + b1), bf16 MFMA ----------------
__global__ __launch_bounds__(256, 2) void mlp1_kernel(
    const ushort_t* __restrict__ z, const ushort_t* __restrict__ Bt,
    const float* __restrict__ bias, ushort_t* __restrict__ outp, int N){
  extern __shared__ char smem[];
  char* As = smem;              // [128 rows][128 k] bf16, XOR-swizzled, 32KB
  char* Bs = smem + 32768;      // [128 cols][128 k] bf16, XOR-swizzled, 32KB
  int tid = threadIdx.x;
  int r0 = blockIdx.x * 128;
  int c0 = blockIdx.y * 128;
  #pragma unroll
  for (int i = 0; i < 8; ++i){
    int g = i * 256 + tid;
    int row = g >> 4, kg = g & 15;
    int lb = row * 256 + ((kg * 16) ^ ((row & 7) << 4));
    int ar = min(r0 + row, N - 1);
    *(bf16x8*)(As + lb) = *(const bf16x8*)(z + (size_t)ar * 128 + kg * 8);
    *(bf16x8*)(Bs + lb) = *(const bf16x8*)(Bt + (size_t)(c0 + row) * 128 + kg * 8);
  }
  __syncthreads();
  int w = tid >> 6, l = tid & 63;
  int wr = w >> 1, wc = w & 1;
  int lr = l & 15, lk = l >> 4;
  f32x4 acc[4][4] = {};
  #pragma unroll
  for (int ks = 0; ks < 4; ++ks){
    int kb = ks * 64 + lk * 16;
    bf16x8 a[4], b[4];
    #pragma unroll
    for (int fm = 0; fm < 4; ++fm){
      int row = wr * 64 + fm * 16 + lr;
      a[fm] = *(const bf16x8*)(As + row * 256 + (kb ^ ((row & 7) << 4)));
    }
    #pragma unroll
    for (int fn = 0; fn < 4; ++fn){
      int col = wc * 64 + fn * 16 + lr;
      b[fn] = *(const bf16x8*)(Bs + col * 256 + (kb ^ ((col & 7) << 4)));
    }
    #pragma unroll
    for (int fm = 0; fm < 4; ++fm)
      #pragma unroll
      for (int fn = 0; fn < 4; ++fn)
        acc[fm][fn] = mfma16(a[fm], b[fn], acc[fm][fn]);
  }
  float bv[4];
  #pragma unroll
  for (int fn = 0; fn < 4; ++fn) bv[fn] = bias[c0 + wc * 64 + fn * 16 + lr];
  #pragma unroll
  for (int fm = 0; fm < 4; ++fm){
    #pragma unroll
    for (int r = 0; r < 4; ++r){
      int row = r0 + wr * 64 + fm * 16 + lk * 4 + r;
      if (row < N){
        #pragma unroll
        for (int fn = 0; fn < 4; ++fn){
          int col = c0 + wc * 64 + fn * 16 + lr;
          outp[(size_t)row * 256 + col] = f2bf(fmaxf(acc[fm][fn][r] + bv[fn], 0.f));
        }
      }
    }
  }
}

// ------- MLP GEMM 2 + bias + LayerNorm + relu + residual (in-place h, + hb mirror) -------
__global__ __launch_bounds__(256, 2) void mlp2_kernel(
    const ushort_t* __restrict__ tin, const ushort_t* __restrict__ Bt,
    const float* __restrict__ b2, const float* __restrict__ gamma,
    const float* __restrict__ beta, float* __restrict__ h,
    ushort_t* __restrict__ hb, int N){
  extern __shared__ char smem[];
  char* As = smem;                     // staging, 32KB (reused per K-half)
  char* Bs = smem + 32768;             // staging, 32KB
  float* z2 = (float*)smem;            // [128][130] f32, overlaps staging (used after)
  float* stat = (float*)(smem + 66560);// mean[128], rstd[128]
  int tid = threadIdx.x;
  int r0 = blockIdx.x * 128;
  int w = tid >> 6, l = tid & 63;
  int wr = w >> 1, wc = w & 1;
  int lr = l & 15, lk = l >> 4;
  f32x4 acc[4][4] = {};
  for (int kh = 0; kh < 2; ++kh){
    #pragma unroll
    for (int i = 0; i < 8; ++i){
      int g = i * 256 + tid;
      int row = g >> 4, kg = g & 15;
      int lb = row * 256 + ((kg * 16) ^ ((row & 7) << 4));
      int ar = min(r0 + row, N - 1);
      *(bf16x8*)(As + lb) = *(const bf16x8*)(tin + (size_t)ar * 256 + kh * 128 + kg * 8);
      *(bf16x8*)(Bs + lb) = *(const bf16x8*)(Bt + (size_t)row * 256 + kh * 128 + kg * 8);
    }
    __syncthreads();
    #pragma unroll
    for (int ks = 0; ks < 4; ++ks){
      int kb = ks * 64 + lk * 16;
      bf16x8 a[4], b[4];
      #pragma unroll
      for (int fm = 0; fm < 4; ++fm){
        int row = wr * 64 + fm * 16 + lr;
        a[fm] = *(const bf16x8*)(As + row * 256 + (kb ^ ((row & 7) << 4)));
      }
      #pragma unroll
      for (int fn = 0; fn < 4; ++fn){
        int col = wc * 64 + fn * 16 + lr;
        b[fn] = *(const bf16x8*)(Bs + col * 256 + (kb ^ ((col & 7) << 4)));
      }
      #pragma unroll
      for (int fm = 0; fm < 4; ++fm)
        #pragma unroll
        for (int fn = 0; fn < 4; ++fn)
          acc[fm][fn] = mfma16(a[fm], b[fn], acc[fm][fn]);
    }
    __syncthreads();
  }
  // epilogue: z2 = acc + b2 (LDS, stride 130 avoids bank conflicts)
  float bv[4];
  #pragma unroll
  for (int fn = 0; fn < 4; ++fn) bv[fn] = b2[wc * 64 + fn * 16 + lr];
  #pragma unroll
  for (int fm = 0; fm < 4; ++fm)
    #pragma unroll
    for (int r = 0; r < 4; ++r){
      int row = wr * 64 + fm * 16 + lk * 4 + r;
      #pragma unroll
      for (int fn = 0; fn < 4; ++fn){
        int col = wc * 64 + fn * 16 + lr;
        z2[row * 130 + col] = acc[fm][fn][r] + bv[fn];
      }
    }
  __syncthreads();
  // pass 1: per-row mean/rstd (2 threads per row, pair-combine via shfl)
  {
    int row = tid >> 1, hf = tid & 1;
    const float* q = z2 + row * 130 + hf * 64;
    float s = 0.f, qq = 0.f;
    #pragma unroll
    for (int i = 0; i < 32; ++i){
      float2 v = *(const float2*)(q + i * 2);
      s += v.x + v.y; qq += v.x * v.x + v.y * v.y;
    }
    s += __shfl_xor(s, 1, 64);
    qq += __shfl_xor(qq, 1, 64);
    if (hf == 0){
      float mean = s * (1.f / 128.f);
      float var = qq * (1.f / 128.f) - mean * mean;
      stat[row] = mean;
      stat[128 + row] = rsqrtf(var + 1e-5f);
    }
  }
  __syncthreads();
  // pass 2: coalesced transform + relu + residual, write h (f32) + hb (bf16 mirror)
  #pragma unroll 4
  for (int it = 0; it < 32; ++it){
    int row = it * 4 + (tid >> 6);
    int grow = r0 + row;
    if (grow < N){
      int col = (tid & 63) * 2;
      float2 v = *(const float2*)(z2 + row * 130 + col);
      float m = stat[row], rs = stat[128 + row];
      float2 g = *(const float2*)(gamma + col);
      float2 bt = *(const float2*)(beta + col);
      float2 hr = *(const float2*)(h + (size_t)grow * HD + col);
      float2 ov;
      ov.x = fmaxf((v.x - m) * rs * g.x + bt.x, 0.f) + hr.x;
      ov.y = fmaxf((v.y - m) * rs * g.y + bt.y, 0.f) + hr.y;
      *(float2*)(h + (size_t)grow * HD + col) = ov;
      ushort_t b0 = f2bf(ov.x), b1v = f2bf(ov.y);
      *(unsigned*)(hb + (size_t)grow * HD + col) = (unsigned)b0 | ((unsigned)b1v << 16);
    }
  }
}

// ---------------- pool (batch is sorted -> contiguous node ranges) ----------------
__global__ void pool_kernel(const float* __restrict__ h, const int* __restrict__ goff,
                            float* __restrict__ outp, int G){
  int g = blockIdx.x, j = threadIdx.x;
  int s = goff[g], e = goff[g + 1];
  float acc = 0.f;
  for (int i = s; i < e; ++i) acc += h[(size_t)i * HD + j];
  outp[(size_t)g * HD + j] = acc;
}

extern "C" void kernel_launch(void* const* d_in, const int* in_sizes, int n_in,
                              void* d_out, int out_size, void* d_ws, size_t ws_size,
                              hipStream_t stream){
  const float* x     = (const float*)d_in[0];
  const int*   ei    = (const int*)  d_in[1];
  const float* eattr = (const float*)d_in[2];
  const int*   batch = (const int*)  d_in[3];
  const float* Wn    = (const float*)d_in[4];
  const float* bn    = (const float*)d_in[5];
  const float* We    = (const float*)d_in[6];
  const float* be    = (const float*)d_in[7];
  const float* W1    = (const float*)d_in[8];
  const float* b1    = (const float*)d_in[9];
  const float* W2    = (const float*)d_in[10];
  const float* b2    = (const float*)d_in[11];
  const float* gamma = (const float*)d_in[12];
  const float* beta  = (const float*)d_in[13];
  float* outp = (float*)d_out;

  int N = in_sizes[3];
  int E = in_sizes[2] / 4;
  int G = out_size / HD;

  char* base = (char*)d_ws;
  size_t o = 0;
  auto alloc = [&](size_t bytes)->char*{
    char* r = base + o; o = (o + bytes + 255) & ~(size_t)255; return r;
  };
  float*    h    = (float*)   alloc((size_t)N * HD * 4);
  ushort_t* hb   = (ushort_t*)alloc((size_t)N * HD * 2);
  ushort_t* z    = (ushort_t*)alloc((size_t)N * HD * 2);
  ushort_t* t    = (ushort_t*)alloc((size_t)N * 2 * HD * 2);
  ushort_t* W1t  = (ushort_t*)alloc((size_t)NL * 2 * HD * HD * 2);
  ushort_t* W2t  = (ushort_t*)alloc((size_t)NL * 2 * HD * HD * 2);
  int* deg    = (int*)alloc((size_t)N * 4);
  int* gdeg   = (int*)alloc((size_t)G * 4);
  int* off    = (int*)alloc((size_t)(N + 1) * 4);
  int* goff   = (int*)alloc((size_t)(G + 1) * 4);
  int* cursor = (int*)alloc((size_t)N * 4);
  int* srcs_s = (int*)alloc((size_t)E * 4);
  float4* ea4 = (float4*)alloc((size_t)E * 16);
  (void)ws_size; (void)n_in;

  const int* src = ei;
  const int* dst = ei + E;

  hipMemsetAsync(deg, 0, (size_t)N * 4, stream);
  hipMemsetAsync(gdeg, 0, (size_t)G * 4, stream);

  hist_kernel<<<(E + 255) / 256, 256, 0, stream>>>(dst, deg, E);
  ghist_kernel<<<(N + 255) / 256, 256, 0, stream>>>(batch, gdeg, N);
  scan_excl<<<1, 1024, 0, stream>>>(deg, off, cursor, N);
  scan_excl<<<1, 1024, 0, stream>>>(gdeg, goff, (int*)nullptr, G);
  scatter_kernel<<<(E + 255) / 256, 256, 0, stream>>>(src, dst, (const float4*)eattr,
                                                      cursor, srcs_s, ea4, E);
  wconv_kernel<<<(2 * NL * 32768) / 256, 256, 0, stream>>>(W1, W2, W1t, W2t);
  encoder_kernel<<<N, HD, 0, stream>>>(x, Wn, bn, h, hb, N);

  int mblocks = (N + 127) / 128;
  for (int l = 0; l < NL; ++l){
    agg_kernel<<<N, HD, 0, stream>>>(h, hb, off, srcs_s, ea4, We, be, z, N);
    mlp1_kernel<<<dim3(mblocks, 2), 256, 65536, stream>>>(
        z, W1t + (size_t)l * 2 * HD * HD, b1 + l * 2 * HD, t, N);
    mlp2_kernel<<<mblocks, 256, 67584, stream>>>(
        t, W2t + (size_t)l * 2 * HD * HD, b2 + l * HD, gamma + l * HD, beta + l * HD, h, hb, N);
  }
  pool_kernel<<<G, HD, 0, stream>>>(h, goff, outp, G);
}

// Round 3
// 446.973 us; speedup vs baseline: 1.4562x; 1.2023x over previous
//
#include <hip/hip_runtime.h>

typedef unsigned short ushort_t;
typedef __attribute__((ext_vector_type(8))) __bf16 bf16x8;
typedef __attribute__((ext_vector_type(4))) float f32x4;

#define HD 128
#define NL 4
#define SCAN_C 2048   // elements per scan block (256 thr x 8)

__device__ __forceinline__ ushort_t f2bf(float f){
  unsigned u = __builtin_bit_cast(unsigned, f);
  unsigned r = (u + 0x7FFFu + ((u >> 16) & 1u)) >> 16;
  return (ushort_t)r;
}

__device__ __forceinline__ float bf2f(ushort_t u){
  unsigned v = ((unsigned)u) << 16;
  return __builtin_bit_cast(float, v);
}

__device__ __forceinline__ f32x4 mfma16(bf16x8 a, bf16x8 b, f32x4 c){
  return __builtin_amdgcn_mfma_f32_16x16x32_bf16(a, b, c, 0, 0, 0);
}

// ---------------- prep kernels ----------------
__global__ void hist_kernel(const int* __restrict__ dst, int* __restrict__ deg, int E){
  int e = blockIdx.x * 256 + threadIdx.x;
  if (e < E) atomicAdd(&deg[dst[e]], 1);
}

__global__ void ghist_kernel(const int* __restrict__ batch, int* __restrict__ gdeg, int N){
  int n = blockIdx.x * 256 + threadIdx.x;
  if (n < N) atomicAdd(&gdeg[batch[n]], 1);
}

// ---- multi-block exclusive scan: part -> top -> final ----
__global__ void scan_part(const int* __restrict__ in, int* __restrict__ bsum, int n){
  int b = blockIdx.x, tid = threadIdx.x;
  int base = b * SCAN_C + tid * 8;
  int s = 0;
  if (base + 8 <= n){
    int4 a = *(const int4*)(in + base);
    int4 c = *(const int4*)(in + base + 4);
    s = a.x + a.y + a.z + a.w + c.x + c.y + c.z + c.w;
  } else {
    #pragma unroll
    for (int k = 0; k < 8; ++k) if (base + k < n) s += in[base + k];
  }
  #pragma unroll
  for (int o = 1; o < 64; o <<= 1) s += __shfl_xor(s, o, 64);
  __shared__ int ws[4];
  int lane = tid & 63, wid = tid >> 6;
  if (lane == 0) ws[wid] = s;
  __syncthreads();
  if (tid == 0) bsum[b] = ws[0] + ws[1] + ws[2] + ws[3];
}

// 1 block, 256 threads; B <= 256. Writes exclusive offsets + grand total to *outn.
__global__ void scan_top(const int* __restrict__ bsum, int* __restrict__ bofs,
                         int* __restrict__ outn, int B){
  int tid = threadIdx.x;
  int v = (tid < B) ? bsum[tid] : 0;
  int lane = tid & 63, wid = tid >> 6;
  int inc = v;
  #pragma unroll
  for (int o = 1; o < 64; o <<= 1){
    int t = __shfl_up(inc, o, 64);
    if (lane >= o) inc += t;
  }
  __shared__ int ws[4];
  if (lane == 63) ws[wid] = inc;
  __syncthreads();
  int wprev = 0;
  for (int i = 0; i < wid; ++i) wprev += ws[i];
  if (tid < B) bofs[tid] = inc - v + wprev;
  if (tid == 0) *outn = ws[0] + ws[1] + ws[2] + ws[3];
}

__global__ void scan_final(const int* __restrict__ in, const int* __restrict__ bofs,
                           int* __restrict__ out, int* __restrict__ cur, int n){
  int b = blockIdx.x, tid = threadIdx.x;
  int base = b * SCAN_C + tid * 8;
  int v[8];
  if (base + 8 <= n){
    *(int4*)(v)     = *(const int4*)(in + base);
    *(int4*)(v + 4) = *(const int4*)(in + base + 4);
  } else {
    #pragma unroll
    for (int k = 0; k < 8; ++k) v[k] = (base + k < n) ? in[base + k] : 0;
  }
  int tsum = 0;
  #pragma unroll
  for (int k = 0; k < 8; ++k) tsum += v[k];
  int lane = tid & 63, wid = tid >> 6;
  int inc = tsum;
  #pragma unroll
  for (int o = 1; o < 64; o <<= 1){
    int t = __shfl_up(inc, o, 64);
    if (lane >= o) inc += t;
  }
  __shared__ int ws[4];
  if (lane == 63) ws[wid] = inc;
  __syncthreads();
  int run = bofs[b] + inc - tsum;
  for (int i = 0; i < wid; ++i) run += ws[i];
  #pragma unroll
  for (int k = 0; k < 8; ++k){
    int i = base + k;
    if (i < n){
      out[i] = run;
      if (cur) cur[i] = run;
      run += v[k];
    }
  }
}

__global__ void scatter_kernel(const int* __restrict__ src, const int* __restrict__ dst,
                               const float4* __restrict__ ea, int* __restrict__ cursor,
                               int* __restrict__ srcs_s, float4* __restrict__ ea4_s, int E){
  int e = blockIdx.x * 256 + threadIdx.x;
  if (e < E){
    int d = dst[e];
    int p = atomicAdd(&cursor[d], 1);
    srcs_s[p] = src[e];
    ea4_s[p] = ea[e];
  }
}

// W1 [L][128][256] -> W1t bf16 [L][256][128]; W2 [L][256][128] -> W2t bf16 [L][128][256]
__global__ void wconv_kernel(const float* __restrict__ W1, const float* __restrict__ W2,
                             ushort_t* __restrict__ W1t, ushort_t* __restrict__ W2t){
  int i = blockIdx.x * 256 + threadIdx.x;
  if (i < NL * 32768){
    int l = i >> 15, r = i & 32767;
    int n = r >> 7, k = r & 127;                 // W1t[l][n][k], n<256, k<128
    W1t[i] = f2bf(W1[l * 32768 + k * 256 + n]);
  } else {
    int i2 = i - NL * 32768;
    int l = i2 >> 15, r = i2 & 32767;
    int n = r >> 8, k = r & 255;                 // W2t[l][n][k], n<128, k<256
    W2t[i2] = f2bf(W2[l * 32768 + k * 128 + n]);
  }
}

// ---------------- encoder ----------------
__global__ void encoder_kernel(const float* __restrict__ x, const float* __restrict__ Wn,
                               const float* __restrict__ bn, float* __restrict__ h,
                               ushort_t* __restrict__ hb, int N){
  int n = blockIdx.x, j = threadIdx.x;
  float acc = bn[j];
  #pragma unroll
  for (int k = 0; k < 9; ++k) acc = fmaf(x[n * 9 + k], Wn[k * HD + j], acc);
  h[(size_t)n * HD + j] = acc;
  hb[(size_t)n * HD + j] = f2bf(acc);
}

// ------- message + aggregate:  z = bf16(h + sum_in relu(hb[src] + ea)) -------
// 4-wide edge unroll: 4 independent bf16 gathers in flight per iteration.
__global__ void agg_kernel(const float* __restrict__ h, const ushort_t* __restrict__ hb,
                           const int* __restrict__ off, const int* __restrict__ srcs,
                           const float4* __restrict__ ea4, const float* __restrict__ We,
                           const float* __restrict__ be, ushort_t* __restrict__ z, int N){
  int n = blockIdx.x, j = threadIdx.x;
  float w0 = We[j], w1 = We[HD + j], w2 = We[2 * HD + j], w3 = We[3 * HD + j];
  float bj = be[j];
  int s = off[n], e = off[n + 1];
  float acc = h[(size_t)n * HD + j];
  int i = s;
  for (; i + 4 <= e; i += 4){
    int s0 = srcs[i], s1 = srcs[i + 1], s2 = srcs[i + 2], s3 = srcs[i + 3];
    float4 a0 = ea4[i], a1 = ea4[i + 1], a2 = ea4[i + 2], a3 = ea4[i + 3];
    float h0 = bf2f(hb[(size_t)s0 * HD + j]);
    float h1 = bf2f(hb[(size_t)s1 * HD + j]);
    float h2 = bf2f(hb[(size_t)s2 * HD + j]);
    float h3 = bf2f(hb[(size_t)s3 * HD + j]);
    float e0 = fmaf(a0.x, w0, fmaf(a0.y, w1, fmaf(a0.z, w2, fmaf(a0.w, w3, bj))));
    float e1 = fmaf(a1.x, w0, fmaf(a1.y, w1, fmaf(a1.z, w2, fmaf(a1.w, w3, bj))));
    float e2 = fmaf(a2.x, w0, fmaf(a2.y, w1, fmaf(a2.z, w2, fmaf(a2.w, w3, bj))));
    float e3 = fmaf(a3.x, w0, fmaf(a3.y, w1, fmaf(a3.z, w2, fmaf(a3.w, w3, bj))));
    acc += fmaxf(h0 + e0, 0.f);
    acc += fmaxf(h1 + e1, 0.f);
    acc += fmaxf(h2 + e2, 0.f);
    acc += fmaxf(h3 + e3, 0.f);
  }
  for (; i < e; ++i){
    int sc = srcs[i];
    float4 a = ea4[i];
    float eav = fmaf(a.x, w0, fmaf(a.y, w1, fmaf(a.z, w2, fmaf(a.w, w3, bj))));
    acc += fmaxf(bf2f(hb[(size_t)sc * HD + j]) + eav, 0.f);
  }
  z[(size_t)n * HD + j] = f2bf(acc);
}

// ---------------- MLP GEMM 1: t = relu(z @ W1 + b1), bf16 MFMA ----------------
__global__ __launch_bounds__(256, 2) void mlp1_kernel(
    const ushort_t* __restrict__ z, const ushort_t* __restrict__ Bt,
    const float* __restrict__ bias, ushort_t* __restrict__ outp, int N){
  extern __shared__ char smem[];
  char* As = smem;              // [128 rows][128 k] bf16, XOR-swizzled, 32KB
  char* Bs = smem + 32768;      // [128 cols][128 k] bf16, XOR-swizzled, 32KB
  int tid = threadIdx.x;
  int r0 = blockIdx.x * 128;
  int c0 = blockIdx.y * 128;
  #pragma unroll
  for (int i = 0; i < 8; ++i){
    int g = i * 256 + tid;
    int row = g >> 4, kg = g & 15;
    int lb = row * 256 + ((kg * 16) ^ ((row & 7) << 4));
    int ar = min(r0 + row, N - 1);
    *(bf16x8*)(As + lb) = *(const bf16x8*)(z + (size_t)ar * 128 + kg * 8);
    *(bf16x8*)(Bs + lb) = *(const bf16x8*)(Bt + (size_t)(c0 + row) * 128 + kg * 8);
  }
  __syncthreads();
  int w = tid >> 6, l = tid & 63;
  int wr = w >> 1, wc = w & 1;
  int lr = l & 15, lk = l >> 4;
  f32x4 acc[4][4] = {};
  #pragma unroll
  for (int ks = 0; ks < 4; ++ks){
    int kb = ks * 64 + lk * 16;
    bf16x8 a[4], b[4];
    #pragma unroll
    for (int fm = 0; fm < 4; ++fm){
      int row = wr * 64 + fm * 16 + lr;
      a[fm] = *(const bf16x8*)(As + row * 256 + (kb ^ ((row & 7) << 4)));
    }
    #pragma unroll
    for (int fn = 0; fn < 4; ++fn){
      int col = wc * 64 + fn * 16 + lr;
      b[fn] = *(const bf16x8*)(Bs + col * 256 + (kb ^ ((col & 7) << 4)));
    }
    #pragma unroll
    for (int fm = 0; fm < 4; ++fm)
      #pragma unroll
      for (int fn = 0; fn < 4; ++fn)
        acc[fm][fn] = mfma16(a[fm], b[fn], acc[fm][fn]);
  }
  float bv[4];
  #pragma unroll
  for (int fn = 0; fn < 4; ++fn) bv[fn] = bias[c0 + wc * 64 + fn * 16 + lr];
  #pragma unroll
  for (int fm = 0; fm < 4; ++fm){
    #pragma unroll
    for (int r = 0; r < 4; ++r){
      int row = r0 + wr * 64 + fm * 16 + lk * 4 + r;
      if (row < N){
        #pragma unroll
        for (int fn = 0; fn < 4; ++fn){
          int col = c0 + wc * 64 + fn * 16 + lr;
          outp[(size_t)row * 256 + col] = f2bf(fmaxf(acc[fm][fn][r] + bv[fn], 0.f));
        }
      }
    }
  }
}

// ------- MLP GEMM 2 + bias + LayerNorm + relu + residual (in-place h, + hb mirror) -------
__global__ __launch_bounds__(256, 2) void mlp2_kernel(
    const ushort_t* __restrict__ tin, const ushort_t* __restrict__ Bt,
    const float* __restrict__ b2, const float* __restrict__ gamma,
    const float* __restrict__ beta, float* __restrict__ h,
    ushort_t* __restrict__ hb, int N){
  extern __shared__ char smem[];
  char* As = smem;                     // staging, 32KB (reused per K-half)
  char* Bs = smem + 32768;             // staging, 32KB
  float* z2 = (float*)smem;            // [128][130] f32, overlaps staging (used after)
  float* stat = (float*)(smem + 66560);// mean[128], rstd[128]
  int tid = threadIdx.x;
  int r0 = blockIdx.x * 128;
  int w = tid >> 6, l = tid & 63;
  int wr = w >> 1, wc = w & 1;
  int lr = l & 15, lk = l >> 4;
  f32x4 acc[4][4] = {};
  for (int kh = 0; kh < 2; ++kh){
    #pragma unroll
    for (int i = 0; i < 8; ++i){
      int g = i * 256 + tid;
      int row = g >> 4, kg = g & 15;
      int lb = row * 256 + ((kg * 16) ^ ((row & 7) << 4));
      int ar = min(r0 + row, N - 1);
      *(bf16x8*)(As + lb) = *(const bf16x8*)(tin + (size_t)ar * 256 + kh * 128 + kg * 8);
      *(bf16x8*)(Bs + lb) = *(const bf16x8*)(Bt + (size_t)row * 256 + kh * 128 + kg * 8);
    }
    __syncthreads();
    #pragma unroll
    for (int ks = 0; ks < 4; ++ks){
      int kb = ks * 64 + lk * 16;
      bf16x8 a[4], b[4];
      #pragma unroll
      for (int fm = 0; fm < 4; ++fm){
        int row = wr * 64 + fm * 16 + lr;
        a[fm] = *(const bf16x8*)(As + row * 256 + (kb ^ ((row & 7) << 4)));
      }
      #pragma unroll
      for (int fn = 0; fn < 4; ++fn){
        int col = wc * 64 + fn * 16 + lr;
        b[fn] = *(const bf16x8*)(Bs + col * 256 + (kb ^ ((col & 7) << 4)));
      }
      #pragma unroll
      for (int fm = 0; fm < 4; ++fm)
        #pragma unroll
        for (int fn = 0; fn < 4; ++fn)
          acc[fm][fn] = mfma16(a[fm], b[fn], acc[fm][fn]);
    }
    __syncthreads();
  }
  // epilogue: z2 = acc + b2 (LDS, stride 130 avoids bank conflicts)
  float bv[4];
  #pragma unroll
  for (int fn = 0; fn < 4; ++fn) bv[fn] = b2[wc * 64 + fn * 16 + lr];
  #pragma unroll
  for (int fm = 0; fm < 4; ++fm)
    #pragma unroll
    for (int r = 0; r < 4; ++r){
      int row = wr * 64 + fm * 16 + lk * 4 + r;
      #pragma unroll
      for (int fn = 0; fn < 4; ++fn){
        int col = wc * 64 + fn * 16 + lr;
        z2[row * 130 + col] = acc[fm][fn][r] + bv[fn];
      }
    }
  __syncthreads();
  // pass 1: per-row mean/rstd (2 threads per row, pair-combine via shfl)
  {
    int row = tid >> 1, hf = tid & 1;
    const float* q = z2 + row * 130 + hf * 64;
    float s = 0.f, qq = 0.f;
    #pragma unroll
    for (int i = 0; i < 32; ++i){
      float2 v = *(const float2*)(q + i * 2);
      s += v.x + v.y; qq += v.x * v.x + v.y * v.y;
    }
    s += __shfl_xor(s, 1, 64);
    qq += __shfl_xor(qq, 1, 64);
    if (hf == 0){
      float mean = s * (1.f / 128.f);
      float var = qq * (1.f / 128.f) - mean * mean;
      stat[row] = mean;
      stat[128 + row] = rsqrtf(var + 1e-5f);
    }
  }
  __syncthreads();
  // pass 2: coalesced transform + relu + residual, write h (f32) + hb (bf16 mirror)
  #pragma unroll 4
  for (int it = 0; it < 32; ++it){
    int row = it * 4 + (tid >> 6);
    int grow = r0 + row;
    if (grow < N){
      int col = (tid & 63) * 2;
      float2 v = *(const float2*)(z2 + row * 130 + col);
      float m = stat[row], rs = stat[128 + row];
      float2 g = *(const float2*)(gamma + col);
      float2 bt = *(const float2*)(beta + col);
      float2 hr = *(const float2*)(h + (size_t)grow * HD + col);
      float2 ov;
      ov.x = fmaxf((v.x - m) * rs * g.x + bt.x, 0.f) + hr.x;
      ov.y = fmaxf((v.y - m) * rs * g.y + bt.y, 0.f) + hr.y;
      *(float2*)(h + (size_t)grow * HD + col) = ov;
      ushort_t b0 = f2bf(ov.x), b1v = f2bf(ov.y);
      *(unsigned*)(hb + (size_t)grow * HD + col) = (unsigned)b0 | ((unsigned)b1v << 16);
    }
  }
}

// ---------------- pool (batch is sorted -> contiguous node ranges) ----------------
__global__ void pool_kernel(const float* __restrict__ h, const int* __restrict__ goff,
                            float* __restrict__ outp, int G){
  int g = blockIdx.x, j = threadIdx.x;
  int s = goff[g], e = goff[g + 1];
  float acc = 0.f;
  for (int i = s; i < e; ++i) acc += h[(size_t)i * HD + j];
  outp[(size_t)g * HD + j] = acc;
}

extern "C" void kernel_launch(void* const* d_in, const int* in_sizes, int n_in,
                              void* d_out, int out_size, void* d_ws, size_t ws_size,
                              hipStream_t stream){
  const float* x     = (const float*)d_in[0];
  const int*   ei    = (const int*)  d_in[1];
  const float* eattr = (const float*)d_in[2];
  const int*   batch = (const int*)  d_in[3];
  const float* Wn    = (const float*)d_in[4];
  const float* bn    = (const float*)d_in[5];
  const float* We    = (const float*)d_in[6];
  const float* be    = (const float*)d_in[7];
  const float* W1    = (const float*)d_in[8];
  const float* b1    = (const float*)d_in[9];
  const float* W2    = (const float*)d_in[10];
  const float* b2    = (const float*)d_in[11];
  const float* gamma = (const float*)d_in[12];
  const float* beta  = (const float*)d_in[13];
  float* outp = (float*)d_out;

  int N = in_sizes[3];
  int E = in_sizes[2] / 4;
  int G = out_size / HD;

  char* base = (char*)d_ws;
  size_t o = 0;
  auto alloc = [&](size_t bytes)->char*{
    char* r = base + o; o = (o + bytes + 255) & ~(size_t)255; return r;
  };
  float*    h    = (float*)   alloc((size_t)N * HD * 4);
  ushort_t* hb   = (ushort_t*)alloc((size_t)N * HD * 2);
  ushort_t* z    = (ushort_t*)alloc((size_t)N * HD * 2);
  ushort_t* t    = (ushort_t*)alloc((size_t)N * 2 * HD * 2);
  ushort_t* W1t  = (ushort_t*)alloc((size_t)NL * 2 * HD * HD * 2);
  ushort_t* W2t  = (ushort_t*)alloc((size_t)NL * 2 * HD * HD * 2);
  int* deg    = (int*)alloc((size_t)N * 4);
  int* gdeg   = (int*)alloc((size_t)G * 4);
  int* off    = (int*)alloc((size_t)(N + 1) * 4);
  int* goff   = (int*)alloc((size_t)(G + 1) * 4);
  int* cursor = (int*)alloc((size_t)N * 4);
  int* bsumN  = (int*)alloc(512 * 4);
  int* bofsN  = (int*)alloc(512 * 4);
  int* bsumG  = (int*)alloc(512 * 4);
  int* bofsG  = (int*)alloc(512 * 4);
  int* srcs_s = (int*)alloc((size_t)E * 4);
  float4* ea4 = (float4*)alloc((size_t)E * 16);
  (void)ws_size; (void)n_in;

  const int* src = ei;
  const int* dst = ei + E;

  hipMemsetAsync(deg, 0, (size_t)N * 4, stream);
  hipMemsetAsync(gdeg, 0, (size_t)G * 4, stream);

  hist_kernel<<<(E + 255) / 256, 256, 0, stream>>>(dst, deg, E);
  ghist_kernel<<<(N + 255) / 256, 256, 0, stream>>>(batch, gdeg, N);

  int BN = (N + SCAN_C - 1) / SCAN_C;
  int BG = (G + SCAN_C - 1) / SCAN_C;
  scan_part<<<BN, 256, 0, stream>>>(deg, bsumN, N);
  scan_top<<<1, 256, 0, stream>>>(bsumN, bofsN, off + N, BN);
  scan_final<<<BN, 256, 0, stream>>>(deg, bofsN, off, cursor, N);
  scan_part<<<BG, 256, 0, stream>>>(gdeg, bsumG, G);
  scan_top<<<1, 256, 0, stream>>>(bsumG, bofsG, goff + G, BG);
  scan_final<<<BG, 256, 0, stream>>>(gdeg, bofsG, goff, (int*)nullptr, G);

  scatter_kernel<<<(E + 255) / 256, 256, 0, stream>>>(src, dst, (const float4*)eattr,
                                                      cursor, srcs_s, ea4, E);
  wconv_kernel<<<(2 * NL * 32768) / 256, 256, 0, stream>>>(W1, W2, W1t, W2t);
  encoder_kernel<<<N, HD, 0, stream>>>(x, Wn, bn, h, hb, N);

  int mblocks = (N + 127) / 128;
  for (int l = 0; l < NL; ++l){
    agg_kernel<<<N, HD, 0, stream>>>(h, hb, off, srcs_s, ea4, We, be, z, N);
    mlp1_kernel<<<dim3(mblocks, 2), 256, 65536, stream>>>(
        z, W1t + (size_t)l * 2 * HD * HD, b1 + l * 2 * HD, t, N);
    mlp2_kernel<<<mblocks, 256, 67584, stream>>>(
        t, W2t + (size_t)l * 2 * HD * HD, b2 + l * HD, gamma + l * HD, beta + l * HD, h, hb, N);
  }
  pool_kernel<<<G, HD, 0, stream>>>(h, goff, outp, G);
}